// Round 1
// baseline (307.662 us; speedup 1.0000x reference)
//
#include <hip/hip_runtime.h>
#include <hip/hip_bf16.h>
#include <stdint.h>

// Shapes fixed by the problem: N=16, C=128, H*W=16384, out_chn=128.
#define NB    16
#define CD    128
#define HW    16384

typedef float  f32x4  __attribute__((ext_vector_type(4)));
typedef short  bf16x8 __attribute__((ext_vector_type(8)));

// fp32 -> bf16 round-to-nearest-even (no NaN handling needed; inputs are normals)
__device__ __forceinline__ unsigned short f2bf(float f) {
    unsigned u = __float_as_uint(f);
    u += 0x7FFFu + ((u >> 16) & 1u);
    return (unsigned short)(u >> 16);
}

// ---------------------------------------------------------------------------
// Kernel 1: G[n] += X_chunk * X_chunk^T  (bf16 MFMA, fp32 atomic accumulate)
// grid (16 n, 16 kchunks), 256 threads. Each block: K-chunk of 1024, in 8
// sub-chunks of 128. LDS tile 128x132 bf16 (pad=+4 elems -> 2-way conflicts,
// free per m136).
// ---------------------------------------------------------------------------
__global__ __launch_bounds__(256) void gram_kernel(const float* __restrict__ x,
                                                   float* __restrict__ G) {
    const int n  = blockIdx.x;
    const int kc = blockIdx.y;
    const int t    = threadIdx.x;
    const int wv   = t >> 6;
    const int lane = t & 63;
    const int q    = lane >> 4;   // 0..3
    const int r16  = lane & 15;

    __shared__ __align__(16) unsigned short Xl[CD * 132];

    f32x4 acc[4][4];
#pragma unroll
    for (int i = 0; i < 4; ++i)
#pragma unroll
        for (int j = 0; j < 4; ++j) acc[i][j] = (f32x4)0.0f;

    const int rt0 = 4 * (wv >> 1);   // row-tile base (of 8 16-wide tiles)
    const int ct0 = 4 * (wv & 1);    // col-tile base

    const float* xb = x + (size_t)n * CD * HW;

    for (int sub = 0; sub < 8; ++sub) {
        const int kbase = kc * 1024 + sub * 128;
        // stage 128 rows x 128 k fp32 -> bf16 LDS (coalesced float4 reads)
#pragma unroll
        for (int i = 0; i < 16; ++i) {
            int f  = i * 256 + t;
            int c  = f >> 5;
            int l4 = (f & 31) * 4;
            float4 v = *(const float4*)(xb + (size_t)c * HW + kbase + l4);
            uint2 pk;
            pk.x = (unsigned)f2bf(v.x) | ((unsigned)f2bf(v.y) << 16);
            pk.y = (unsigned)f2bf(v.z) | ((unsigned)f2bf(v.w) << 16);
            *(uint2*)(&Xl[c * 132 + l4]) = pk;
        }
        __syncthreads();

#pragma unroll
        for (int ks = 0; ks < 4; ++ks) {
            const int k0 = ks * 32 + q * 8;
            bf16x8 af[4], bfr[4];
#pragma unroll
            for (int i = 0; i < 4; ++i) {
                const unsigned short* pa = &Xl[(16 * (rt0 + i) + r16) * 132 + k0];
                union { bf16x8 v; uint2 u[2]; } ua;
                ua.u[0] = *(const uint2*)pa;
                ua.u[1] = *(const uint2*)(pa + 4);
                af[i] = ua.v;
                const unsigned short* pb = &Xl[(16 * (ct0 + i) + r16) * 132 + k0];
                union { bf16x8 v; uint2 u[2]; } ub;
                ub.u[0] = *(const uint2*)pb;
                ub.u[1] = *(const uint2*)(pb + 4);
                bfr[i] = ub.v;
            }
#pragma unroll
            for (int i = 0; i < 4; ++i)
#pragma unroll
                for (int j = 0; j < 4; ++j)
                    acc[i][j] = __builtin_amdgcn_mfma_f32_16x16x32_bf16(
                        af[i], bfr[j], acc[i][j], 0, 0, 0);
        }
        __syncthreads();
    }

    float* Gn = G + (size_t)n * CD * CD;
#pragma unroll
    for (int i = 0; i < 4; ++i)
#pragma unroll
        for (int j = 0; j < 4; ++j)
#pragma unroll
            for (int rr = 0; rr < 4; ++rr) {
                // C/D layout (m89): col = lane&15, row = (lane>>4)*4 + reg
                int row = 16 * (rt0 + i) + q * 4 + rr;
                int col = 16 * (ct0 + j) + r16;
                atomicAdd(&Gn[row * CD + col], acc[i][j][rr]);
            }
}

// ---------------------------------------------------------------------------
// Kernel 2: per-row softmax stats (max, 1/sum(exp)). One wave per row.
// grid 512 blocks x 256 threads -> 2048 rows.
// ---------------------------------------------------------------------------
__global__ __launch_bounds__(256) void rowstats_kernel(const float* __restrict__ G,
                                                       float* __restrict__ mx,
                                                       float* __restrict__ rs) {
    const int row  = blockIdx.x * 4 + (threadIdx.x >> 6);
    const int lane = threadIdx.x & 63;
    const float* g = G + (size_t)row * CD;
    float g0 = g[lane];
    float g1 = g[lane + 64];
    float m = fmaxf(g0, g1);
#pragma unroll
    for (int off = 32; off > 0; off >>= 1) m = fmaxf(m, __shfl_xor(m, off));
    float s = __expf(g0 - m) + __expf(g1 - m);
#pragma unroll
    for (int off = 32; off > 0; off >>= 1) s += __shfl_xor(s, off);
    if (lane == 0) {
        mx[row] = m;
        rs[row] = 1.0f / s;
    }
}

// ---------------------------------------------------------------------------
// Kernel 3: M[n] = conv_w @ softmax(G[n])  -> bf16.  M[o][d] = sum_c cw[o][c]*W[c][d]
// grid (16 n, 8 o-chunks of 16), 256 threads. W computed on the fly into LDS.
// ---------------------------------------------------------------------------
__global__ __launch_bounds__(256) void mmat_kernel(const float* __restrict__ G,
                                                   const float* __restrict__ mx,
                                                   const float* __restrict__ rs,
                                                   const float* __restrict__ cw,
                                                   unsigned short* __restrict__ Mbf) {
    const int n  = blockIdx.x;
    const int bo = blockIdx.y;
    const int t  = threadIdx.x;
    __shared__ __align__(16) float Wl[CD * CD];   // 64 KiB exactly

    const float* Gn  = G  + (size_t)n * CD * CD;
    const float* mxn = mx + n * CD;
    const float* rsn = rs + n * CD;

#pragma unroll 4
    for (int i = 0; i < 64; ++i) {
        int e = i * 256 + t;
        int c = e >> 7;
        int d = e & 127;
        Wl[c * CD + d] = __expf(Gn[c * CD + d] - mxn[c]) * rsn[c];
    }
    __syncthreads();

    const int o  = bo * 16 + (t >> 4);
    const int d0 = (t & 15) * 8;
    float a0 = 0, a1 = 0, a2 = 0, a3 = 0, a4 = 0, a5 = 0, a6 = 0, a7 = 0;
    const float* cwo = cw + (size_t)o * CD;
#pragma unroll 4
    for (int c = 0; c < CD; ++c) {
        float cv = cwo[c];
        float4 w0 = *(const float4*)&Wl[c * CD + d0];
        float4 w1 = *(const float4*)&Wl[c * CD + d0 + 4];
        a0 += cv * w0.x; a1 += cv * w0.y; a2 += cv * w0.z; a3 += cv * w0.w;
        a4 += cv * w1.x; a5 += cv * w1.y; a6 += cv * w1.z; a7 += cv * w1.w;
    }
    uint4 pk;
    pk.x = (unsigned)f2bf(a0) | ((unsigned)f2bf(a1) << 16);
    pk.y = (unsigned)f2bf(a2) | ((unsigned)f2bf(a3) << 16);
    pk.z = (unsigned)f2bf(a4) | ((unsigned)f2bf(a5) << 16);
    pk.w = (unsigned)f2bf(a6) | ((unsigned)f2bf(a7) << 16);
    *(uint4*)&Mbf[((size_t)n * CD + o) * CD + d0] = pk;
}

// ---------------------------------------------------------------------------
// Kernel 4: out[n] = M[n] @ X[n] + bias.  grid (128 l-chunks, 16 n), 256 thr.
// A-frags (M, bf16) loaded from L2 straight into registers (held across the
// whole block). X tile staged TRANSPOSED ([l][d], d contiguous) so B-frags are
// contiguous ds reads.
// ---------------------------------------------------------------------------
__global__ __launch_bounds__(256) void out_kernel(const float* __restrict__ x,
                                                  const unsigned short* __restrict__ Mbf,
                                                  const float* __restrict__ bias,
                                                  float* __restrict__ out) {
    const int lb = blockIdx.x;      // 128 chunks of 128 columns
    const int n  = blockIdx.y;
    const int l0 = lb * 128;
    const int t    = threadIdx.x;
    const int wv   = t >> 6;
    const int lane = t & 63;
    const int q    = lane >> 4;
    const int r16  = lane & 15;

    __shared__ __align__(16) unsigned short Xt[128 * 132];  // [l][d], pad +4
    __shared__ float bl[CD];

    const int ot0 = 4 * (wv >> 1);
    const int lt0 = 4 * (wv & 1);

    // A-frags: A[m=o][k=d], lane holds M[o = 16*ot + (lane&15)][k0 .. k0+7]
    bf16x8 af[4][4];
    const unsigned short* Mn = Mbf + (size_t)n * CD * CD;
#pragma unroll
    for (int i = 0; i < 4; ++i)
#pragma unroll
        for (int ks = 0; ks < 4; ++ks) {
            int o = 16 * (ot0 + i) + r16;
            int k = ks * 32 + q * 8;
            union { bf16x8 v; uint4 u; } ua;
            ua.u = *(const uint4*)(&Mn[o * CD + k]);
            af[i][ks] = ua.v;
        }

    if (t < CD) bl[t] = bias[t];

    // Stage X[n][d][l0..l0+127] fp32 -> bf16, transposed into Xt[l][d]
    const float* xb = x + (size_t)n * CD * HW + l0;
#pragma unroll
    for (int i = 0; i < 16; ++i) {
        int f  = i * 256 + t;
        int d  = f >> 5;
        int l4 = (f & 31) * 4;
        float4 v = *(const float4*)(xb + (size_t)d * HW + l4);
        Xt[(l4 + 0) * 132 + d] = f2bf(v.x);
        Xt[(l4 + 1) * 132 + d] = f2bf(v.y);
        Xt[(l4 + 2) * 132 + d] = f2bf(v.z);
        Xt[(l4 + 3) * 132 + d] = f2bf(v.w);
    }
    __syncthreads();

    f32x4 acc[4][4];
#pragma unroll
    for (int i = 0; i < 4; ++i)
#pragma unroll
        for (int j = 0; j < 4; ++j) acc[i][j] = (f32x4)0.0f;

#pragma unroll
    for (int ks = 0; ks < 4; ++ks) {
        bf16x8 bfr[4];
#pragma unroll
        for (int j = 0; j < 4; ++j) {
            // B[k=d][col=l]: lane holds X[d = ks*32+q*8+jj][l = 16*lt + (lane&15)]
            const unsigned short* pb = &Xt[(16 * (lt0 + j) + r16) * 132 + ks * 32 + q * 8];
            union { bf16x8 v; uint2 u[2]; } ub;
            ub.u[0] = *(const uint2*)pb;
            ub.u[1] = *(const uint2*)(pb + 4);
            bfr[j] = ub.v;
        }
#pragma unroll
        for (int i = 0; i < 4; ++i)
#pragma unroll
            for (int j = 0; j < 4; ++j)
                acc[i][j] = __builtin_amdgcn_mfma_f32_16x16x32_bf16(
                    af[i][ks], bfr[j], acc[i][j], 0, 0, 0);
    }

    float* ob = out + (size_t)n * CD * HW + l0;
#pragma unroll
    for (int i = 0; i < 4; ++i)
#pragma unroll
        for (int j = 0; j < 4; ++j)
#pragma unroll
            for (int rr = 0; rr < 4; ++rr) {
                int o = 16 * (ot0 + i) + q * 4 + rr;
                int l = 16 * (lt0 + j) + r16;
                ob[(size_t)o * HW + l] = acc[i][j][rr] + bl[o];
            }
}

// ---------------------------------------------------------------------------
extern "C" void kernel_launch(void* const* d_in, const int* in_sizes, int n_in,
                              void* d_out, int out_size, void* d_ws, size_t ws_size,
                              hipStream_t stream) {
    const float* x  = (const float*)d_in[0];   // (16,128,128,128) fp32
    const float* cw = (const float*)d_in[1];   // (128,128) fp32
    const float* cb = (const float*)d_in[2];   // (128,) fp32
    float* out = (float*)d_out;                // (16,128,128,128) fp32

    char* ws = (char*)d_ws;
    float*          G   = (float*)(ws);                      // 1 MiB
    float*          mxp = (float*)(ws + (1u << 20));         // 8 KiB
    float*          rsp = (float*)(ws + (1u << 20) + 8192);  // 8 KiB
    unsigned short* Mbf = (unsigned short*)(ws + (1u << 20) + 16384); // 512 KiB

    hipMemsetAsync(G, 0, (size_t)NB * CD * CD * sizeof(float), stream);

    gram_kernel   <<<dim3(NB, 16), 256, 0, stream>>>(x, G);
    rowstats_kernel<<<dim3(512),    256, 0, stream>>>(G, mxp, rsp);
    mmat_kernel   <<<dim3(NB, 8),  256, 0, stream>>>(G, mxp, rsp, cw, Mbf);
    out_kernel    <<<dim3(128, NB), 256, 0, stream>>>(x, Mbf, cb, out);
}